// Round 1
// baseline (262.937 us; speedup 1.0000x reference)
//
#include <hip/hip_runtime.h>

typedef __attribute__((ext_vector_type(4))) float floatx4;
typedef __attribute__((ext_vector_type(8))) short short8;

__device__ __forceinline__ unsigned short f2bf(float f) {
    union { float f; unsigned int i; } v; v.f = f;
    unsigned int x = v.i;
    unsigned int r = (x + 0x7FFFu + ((x >> 16) & 1u)) >> 16;   // RNE
    return (unsigned short)r;
}
__device__ __forceinline__ float bf2f(unsigned short u) {
    union { unsigned int i; float f; } v; v.i = ((unsigned int)u) << 16;
    return v.f;
}

// ---------------- prep: rearrange phi (1024x24) and W (256x256) into bf16
// MFMA B-fragment order in workspace.
// phiF: [kstep 0..31][ntile 0..1][lane 0..63][j 0..7]  (32768 bf16 = 64KB)
// WF  : [ntile 0..15][kstep 0..7][lane 0..63][j 0..7]  (65536 bf16 = 128KB)
// B-fragment: lane holds B[k = (lane>>4)*8 + j][n = lane&15]; B[k][n] = W[n][k] / phi[k][n]
__global__ void mhc_prep(const float* __restrict__ phi, const float* __restrict__ W,
                         unsigned short* __restrict__ phiF, unsigned short* __restrict__ WF) {
    int e = blockIdx.x * 256 + threadIdx.x;
    if (e < 32768) {
        int j = e & 7, lane = (e >> 3) & 63, nt = (e >> 9) & 1, ks = e >> 10;
        int n = nt * 16 + (lane & 15);
        int k = ks * 32 + ((lane >> 4) & 3) * 8 + j;
        float v = (n < 24) ? phi[k * 24 + n] : 0.0f;
        phiF[e] = f2bf(v);
    } else {
        int e2 = e - 32768;
        int j = e2 & 7, lane = (e2 >> 3) & 63, ks = (e2 >> 9) & 7, nt = e2 >> 12;
        int n = nt * 16 + (lane & 15);
        int k = ks * 32 + ((lane >> 4) & 3) * 8 + j;
        WF[e2] = f2bf(W[n * 256 + k]);
    }
}

// ---------------- main fused kernel: 16 tokens per block -------------------
#define XS_STRIDE 1032   // 1024 + 8 bf16 pad (2064B = 129*16: 16B aligned, banks spread)
#define XIN_STRIDE 264   // 256 + 8 bf16 pad (528B = 33*16)
#define CO_STRIDE 28     // floats, 112B (16B aligned)

__global__ __launch_bounds__(256) void mhc_main(
    const float* __restrict__ x, const float* __restrict__ bias,
    const float* __restrict__ s_ap, const float* __restrict__ s_apo,
    const float* __restrict__ s_ar,
    const unsigned short* __restrict__ phiF, const unsigned short* __restrict__ WF,
    float* __restrict__ out)
{
    __shared__ unsigned short xs[16 * XS_STRIDE];   // x tile, bf16
    __shared__ unsigned short xin[16 * XIN_STRIDE]; // x_in tile, bf16
    __shared__ float lg[16 * CO_STRIDE];            // logits
    __shared__ float coef[16 * CO_STRIDE];          // [hpre0..3, hpost0..3, P[16]]

    const int t = threadIdx.x;
    const int lane = t & 63;
    const int w = t >> 6;
    const int quad = lane >> 4;
    const int col = lane & 15;
    const long base = (long)blockIdx.x * (16 * 1024);

    // ---- phase 0: global fp32 -> bf16 LDS ----
    {
        const float4* xg = (const float4*)(x + base);
        #pragma unroll
        for (int ii = 0; ii < 16; ++ii) {
            int lin = ii * 256 + t;           // float4 index within 16x1024 tile
            float4 v = xg[lin];
            int tok = lin >> 8;
            int k = (lin & 255) * 4;
            uint2 pk;
            pk.x = (unsigned int)f2bf(v.x) | ((unsigned int)f2bf(v.y) << 16);
            pk.y = (unsigned int)f2bf(v.z) | ((unsigned int)f2bf(v.w) << 16);
            *reinterpret_cast<uint2*>(&xs[tok * XS_STRIDE + k]) = pk;
        }
    }
    __syncthreads();

    // ---- phase 1: logits = V(16x1024) @ phi(1024x24), waves 0,1 (ntile = w) ----
    if (w < 2) {
        floatx4 acc = {0.0f, 0.0f, 0.0f, 0.0f};
        for (int ks = 0; ks < 32; ++ks) {
            short8 a = *reinterpret_cast<const short8*>(&xs[col * XS_STRIDE + ks * 32 + quad * 8]);
            short8 b = *reinterpret_cast<const short8*>(&phiF[(ks * 2 + w) * 512 + lane * 8]);
            acc = __builtin_amdgcn_mfma_f32_16x16x32_bf16(a, b, acc, 0, 0, 0);
        }
        int n = w * 16 + col;
        if (n < 24) {
            #pragma unroll
            for (int r = 0; r < 4; ++r)
                lg[(quad * 4 + r) * CO_STRIDE + n] = acc[r];
        }
    }
    __syncthreads();

    // ---- phase 2: rms-norm, sigmoids, Sinkhorn (16 lanes per token) ----
    {
        int g = t >> 4, p = t & 15;
        float a = lg[g * CO_STRIDE + p];
        float b2 = (p < 8) ? lg[g * CO_STRIDE + 16 + p] : 0.0f;
        float s = a * a + b2 * b2;
        s += __shfl_xor(s, 1); s += __shfl_xor(s, 2);
        s += __shfl_xor(s, 4); s += __shfl_xor(s, 8);
        float rinv = 1.0f / sqrtf(s * (1.0f / 24.0f) + 1e-6f);
        float yP = lg[g * CO_STRIDE + 8 + p] * rinv + bias[8 + p];
        float P = expf(s_ar[0] * yP);
        for (int it = 0; it < 20; ++it) {
            float r = P + __shfl_xor(P, 1); r += __shfl_xor(r, 2);   // row sum (axis -1)
            P *= __builtin_amdgcn_rcpf(r + 1e-6f);
            float c = P + __shfl_xor(P, 4); c += __shfl_xor(c, 8);   // col sum (axis -2)
            P *= __builtin_amdgcn_rcpf(c + 1e-6f);
        }
        coef[g * CO_STRIDE + 8 + p] = P;
        if (p < 8) {
            float yh = a * rinv + bias[p];
            float h = (p < 4) ? 1.0f / (1.0f + expf(-s_ap[0] * yh))
                              : 2.0f / (1.0f + expf(-s_apo[0] * yh));
            coef[g * CO_STRIDE + p] = h;
        }
    }
    __syncthreads();

    // ---- phase 3: x_in[tok][c] = sum_i hpre[i] * x[tok][i][c], c = t ----
    {
        int c = t;
        #pragma unroll 4
        for (int tok = 0; tok < 16; ++tok) {
            float4 h4 = *reinterpret_cast<const float4*>(&coef[tok * CO_STRIDE]);
            const unsigned short* xr = &xs[tok * XS_STRIDE + c];
            float s = h4.x * bf2f(xr[0]) + h4.y * bf2f(xr[256])
                    + h4.z * bf2f(xr[512]) + h4.w * bf2f(xr[768]);
            xin[tok * XIN_STRIDE + c] = f2bf(s);
        }
    }
    __syncthreads();

    // ---- phase 4: f_out = Xin(16x256) @ W^T, wave w does ntiles 4w..4w+3 ----
    short8 afr[8];
    #pragma unroll
    for (int ks = 0; ks < 8; ++ks)
        afr[ks] = *reinterpret_cast<const short8*>(&xin[col * XIN_STRIDE + ks * 32 + quad * 8]);
    floatx4 accs[4];
    #pragma unroll
    for (int nt = 0; nt < 4; ++nt) {
        floatx4 acc = {0.0f, 0.0f, 0.0f, 0.0f};
        int ntile = w * 4 + nt;
        #pragma unroll
        for (int ks = 0; ks < 8; ++ks) {
            short8 b = *reinterpret_cast<const short8*>(&WF[(ntile * 8 + ks) * 512 + lane * 8]);
            acc = __builtin_amdgcn_mfma_f32_16x16x32_bf16(afr[ks], b, acc, 0, 0, 0);
        }
        accs[nt] = acc;
    }

    // ---- phase 5: out[tok][o][c] = sum_i P[o][i] x[tok][i][c] + hpost[o]*f_out[tok][c] ----
    #pragma unroll
    for (int r = 0; r < 4; ++r) {
        int tok = quad * 4 + r;
        const float* cb = &coef[tok * CO_STRIDE];
        float4 hpo = *reinterpret_cast<const float4*>(cb + 4);
        float4 P0  = *reinterpret_cast<const float4*>(cb + 8);
        float4 P1  = *reinterpret_cast<const float4*>(cb + 12);
        float4 P2  = *reinterpret_cast<const float4*>(cb + 16);
        float4 P3  = *reinterpret_cast<const float4*>(cb + 20);
        long ob = base + (long)tok * 1024;
        #pragma unroll
        for (int nt = 0; nt < 4; ++nt) {
            int c = (w * 4 + nt) * 16 + col;
            float f = accs[nt][r];
            const unsigned short* xr = &xs[tok * XS_STRIDE + c];
            float x0 = bf2f(xr[0]),   x1 = bf2f(xr[256]);
            float x2 = bf2f(xr[512]), x3 = bf2f(xr[768]);
            out[ob + c]       = P0.x * x0 + P0.y * x1 + P0.z * x2 + P0.w * x3 + hpo.x * f;
            out[ob + 256 + c] = P1.x * x0 + P1.y * x1 + P1.z * x2 + P1.w * x3 + hpo.y * f;
            out[ob + 512 + c] = P2.x * x0 + P2.y * x1 + P2.z * x2 + P2.w * x3 + hpo.z * f;
            out[ob + 768 + c] = P3.x * x0 + P3.y * x1 + P3.z * x2 + P3.w * x3 + hpo.w * f;
        }
    }
}

extern "C" void kernel_launch(void* const* d_in, const int* in_sizes, int n_in,
                              void* d_out, int out_size, void* d_ws, size_t ws_size,
                              hipStream_t stream) {
    const float* x    = (const float*)d_in[0];
    const float* phi  = (const float*)d_in[1];
    const float* bias = (const float*)d_in[2];
    const float* ap   = (const float*)d_in[3];
    const float* apo  = (const float*)d_in[4];
    const float* ar   = (const float*)d_in[5];
    const float* W    = (const float*)d_in[6];
    float* out = (float*)d_out;

    unsigned short* phiF = (unsigned short*)d_ws;           // 32768 bf16
    unsigned short* WF   = (unsigned short*)d_ws + 32768;   // 65536 bf16

    mhc_prep<<<384, 256, 0, stream>>>(phi, W, phiF, WF);
    mhc_main<<<2048, 256, 0, stream>>>(x, bias, ap, apo, ar, phiF, WF, out);
}